// Round 3
// baseline (232.788 us; speedup 1.0000x reference)
//
#include <hip/hip_runtime.h>

// Problem constants
#define HW    1024
#define C_DIM 256
#define P_DIM 512
#define NPOS  65536          // B*HW = 64*1024
#define NT    32             // positions per block
#define NOUT  16777216       // B*C*HW recon elements

// ---------------------------------------------------------------------------
// Kernel 1: normalize prototypes over C and write TRANSPOSED pnT[c][p]
// so the GEMM kernel reads pnT[k*512 + p] coalesced per-lane.
// ---------------------------------------------------------------------------
__global__ __launch_bounds__(256) void proto_norm_kernel(
    const float* __restrict__ proto, float* __restrict__ pnT) {
  int p = blockIdx.x;       // 0..511
  int c = threadIdx.x;      // 0..255
  float v = proto[p * C_DIM + c];
  float s = v * v;
  #pragma unroll
  for (int off = 32; off > 0; off >>= 1) s += __shfl_down(s, off);
  __shared__ float red[4];
  int lane = c & 63, wid = c >> 6;
  if (lane == 0) red[wid] = s;
  __syncthreads();
  float tot = red[0] + red[1] + red[2] + red[3];
  float nrm = fmaxf(sqrtf(tot), 1e-12f);
  pnT[c * P_DIM + p] = v / nrm;
}

// ---------------------------------------------------------------------------
// Kernel 2: fused scores + argmax + recon gather.
// Block: 512 threads = 8 waves. Block owns NT=32 consecutive positions
// (all within one b). Wave w owns prototypes [w*64, w*64+64), lane <-> p.
// Per k: pk per-lane (coalesced, L2-resident pnT), x-values wave-uniform
// (expected to land in SGPRs via s_load), 32 v_fmac with scalar operand.
// ---------------------------------------------------------------------------
__global__ __launch_bounds__(512) void score_argmax_kernel(
    const float* __restrict__ x, const float* __restrict__ proto,
    const float* __restrict__ pnT, float* __restrict__ out) {
  __shared__ float s_v[8][32];
  __shared__ int   s_i[8][32];
  __shared__ int   s_idx[32];

  int t = threadIdx.x;
  int w = t >> 6;
  int lane = t & 63;
  int n0 = blockIdx.x * NT;        // global position
  int b = n0 >> 10;
  int hw0 = n0 & 1023;

  const float* xbase = x + ((size_t)b << 18) + hw0;   // + k*1024 + j
  const float* pcol = pnT + (w << 6) + lane;          // + k*512

  float acc[NT];
  #pragma unroll
  for (int j = 0; j < NT; ++j) acc[j] = 0.f;

  for (int k = 0; k < 256; ++k) {
    float pk = pcol[k << 9];                 // per-lane, coalesced across wave
    const float* xr = xbase + (k << 10);     // wave-uniform address
    #pragma unroll
    for (int j = 0; j < NT; ++j)
      acc[j] = fmaf(xr[j], pk, acc[j]);      // scalar * vector -> acc
  }

  // Per-wave argmax over its 64 prototypes, for each of the 32 positions.
  // Tie-break: lowest p (ffs of equality ballot) == jnp.argmax first-match.
  #pragma unroll 1
  for (int j = 0; j < NT; ++j) {
    float v = acc[j];
    float m = v;
    #pragma unroll
    for (int off = 1; off < 64; off <<= 1) m = fmaxf(m, __shfl_xor(m, off));
    unsigned long long msk = __ballot(v == m);
    if (lane == 0) {
      s_v[w][j] = m;
      s_i[w][j] = (w << 6) + (__ffsll(msk) - 1);
    }
  }
  __syncthreads();

  // Cross-wave merge (ascending wave => ascending p => first-max tie-break),
  // write indices output as float values.
  if (t < NT) {
    float best = s_v[0][t];
    int bi = s_i[0][t];
    #pragma unroll
    for (int g = 1; g < 8; ++g) {
      float vv = s_v[g][t];
      if (vv > best) { best = vv; bi = s_i[g][t]; }
    }
    s_idx[t] = bi;
    out[(size_t)NOUT + n0 + t] = (float)bi;
  }
  __syncthreads();

  // Recon gather: out[b][c][hw0+n] = proto[idx_n][c]; writes coalesced in n.
  float* rb = out + ((size_t)b << 18) + hw0;
  #pragma unroll 1
  for (int cc = 0; cc < 16; ++cc) {
    int cIdx = ((t >> 5) << 4) + cc;   // 16 c-groups x 16 iterations
    int n = t & 31;
    rb[((size_t)cIdx << 10) + n] = proto[(s_idx[n] << 8) + cIdx];
  }
}

extern "C" void kernel_launch(void* const* d_in, const int* in_sizes, int n_in,
                              void* d_out, int out_size, void* d_ws, size_t ws_size,
                              hipStream_t stream) {
  const float* x = (const float*)d_in[0];        // (64, 256, 32, 32) f32
  const float* proto = (const float*)d_in[1];    // (512, 256) f32
  float* out = (float*)d_out;                    // 16777216 recon + 65536 idx
  float* pnT = (float*)d_ws;                     // 256 x 512 f32 = 512 KB

  proto_norm_kernel<<<P_DIM, C_DIM, 0, stream>>>(proto, pnT);
  score_argmax_kernel<<<NPOS / NT, 512, 0, stream>>>(x, proto, pnT, out);
}

// Round 4
// 119.352 us; speedup vs baseline: 1.9504x; 1.9504x over previous
//
#include <hip/hip_runtime.h>
#include <hip/hip_bf16.h>

typedef __attribute__((ext_vector_type(8))) short short8;
typedef __attribute__((ext_vector_type(4))) float f32x4;

#define NPOS  65536
#define NOUT  16777216
#define QCAP  384
#define DELTA 0.05f

// ---------------------------------------------------------------------------
// Kernel 1: normalize prototypes (EXACT same reduce order as the passing
// round-0 kernel -> identical f32 values), write pnN f32 [p][k] and bf16 copy.
// ---------------------------------------------------------------------------
__global__ __launch_bounds__(256) void proto_prep(
    const float* __restrict__ proto, float* __restrict__ pnN,
    ushort* __restrict__ pnBF) {
  int p = blockIdx.x;       // 0..511
  int c = threadIdx.x;      // 0..255
  float v = proto[p * 256 + c];
  float s = v * v;
  #pragma unroll
  for (int off = 32; off > 0; off >>= 1) s += __shfl_down(s, off);
  __shared__ float red[4];
  int lane = c & 63, wid = c >> 6;
  if (lane == 0) red[wid] = s;
  __syncthreads();
  float tot = red[0] + red[1] + red[2] + red[3];
  float nrm = fmaxf(sqrtf(tot), 1e-12f);
  float q = v / nrm;
  pnN[p * 256 + c] = q;
  __hip_bfloat16 h = __float2bfloat16(q);
  pnBF[p * 256 + c] = *reinterpret_cast<ushort*>(&h);
}

// ---------------------------------------------------------------------------
// Kernel 2: per block: 64 positions x 512 protos.
//  - stage x-tile (64 pos x 256 k) -> LDS bf16 [m][k], XOR-swizzled
//  - bf16 MFMA 16x16x32: 8 waves, wave w owns protos [w*64, w*64+64)
//  - block max per position, flag candidates >= max - DELTA
//  - exact fp32 rescore (round-0 arithmetic) of candidates, argmax, gather
// ---------------------------------------------------------------------------
__global__ __launch_bounds__(512, 4) void match_kernel(
    const float* __restrict__ x, const float* __restrict__ proto,
    const float* __restrict__ pnN, const ushort* __restrict__ pnBF,
    float* __restrict__ out) {
  __shared__ __align__(16) float  raw[128 * 64];    // 32 KB (half-K staging)
  __shared__ __align__(16) ushort xbf[64 * 256];    // 32 KB bf16 [m][k] swizzled
  __shared__ float wmax[8][64];
  __shared__ float thr[64];
  __shared__ int   queue[QCAP];
  __shared__ float qscore[QCAP];
  __shared__ int   idxl[64];
  __shared__ int   qn;

  const int t = threadIdx.x;
  const int l = t & 63, w = t >> 6;
  const int g = l >> 4, r8 = l & 7, c16 = l & 15;
  const int n0 = blockIdx.x << 6;          // global position base
  const int b = n0 >> 10, hw0 = n0 & 1023;
  const float* xg = x + ((size_t)b << 18) + hw0;    // + k*1024 + m

  if (t == 0) qn = 0;

  // ---- stage x-tile in two half-K phases (raw fp32 -> transposed bf16) ----
  for (int ph = 0; ph < 2; ++ph) {
    __syncthreads();
    #pragma unroll
    for (int i = 0; i < 4; ++i) {
      int q = t + (i << 9);
      int krel = q >> 4, m4 = (q & 15) << 2;
      const float4* src =
          reinterpret_cast<const float4*>(xg + (((ph << 7) + krel) << 10) + m4);
      *reinterpret_cast<float4*>(&raw[(krel << 6) + m4]) = *src;
    }
    __syncthreads();
    #pragma unroll
    for (int i = 0; i < 2; ++i) {
      int q = t + (i << 9);
      int m = q & 63, cR = q >> 6;           // cR 0..15 (8-k chunk within half)
      short8 pk;
      #pragma unroll
      for (int j = 0; j < 8; ++j) {
        float v = raw[(((cR << 3) + j) << 6) + m];
        __hip_bfloat16 h = __float2bfloat16(v);
        pk[j] = *reinterpret_cast<short*>(&h);
      }
      int chunk = (ph << 4) + cR;            // absolute 16B chunk 0..31
      int dst = (m << 8) + ((chunk ^ (m & 7)) << 3);
      *reinterpret_cast<short8*>(&xbf[dst]) = pk;
    }
  }
  __syncthreads();

  // ---- bf16 GEMM: D[m][n] = sum_k x[m][k] * pn[n][k] ----
  const ushort* pB0 = pnBF + (((w << 6) + c16) << 8) + (g << 3);
  f32x4 acc[4][4];
  #pragma unroll
  for (int mi = 0; mi < 4; ++mi)
    #pragma unroll
    for (int ni = 0; ni < 4; ++ni) acc[mi][ni] = (f32x4){0.f, 0.f, 0.f, 0.f};

  short8 Bcur[4], Bnxt[4];
  #pragma unroll
  for (int ni = 0; ni < 4; ++ni)
    Bcur[ni] = *reinterpret_cast<const short8*>(pB0 + (ni << 12));

  #pragma unroll
  for (int ks = 0; ks < 8; ++ks) {
    if (ks < 7) {
      #pragma unroll
      for (int ni = 0; ni < 4; ++ni)
        Bnxt[ni] = *reinterpret_cast<const short8*>(pB0 + (ni << 12) + ((ks + 1) << 5));
    }
    #pragma unroll
    for (int mi = 0; mi < 4; ++mi) {
      int chunk = (ks << 2) + g;
      const short8 a = *reinterpret_cast<const short8*>(
          &xbf[(((mi << 4) + c16) << 8) + ((chunk ^ r8) << 3)]);
      #pragma unroll
      for (int ni = 0; ni < 4; ++ni)
        acc[mi][ni] =
            __builtin_amdgcn_mfma_f32_16x16x32_bf16(a, Bcur[ni], acc[mi][ni], 0, 0, 0);
    }
    if (ks < 7) {
      #pragma unroll
      for (int ni = 0; ni < 4; ++ni) Bcur[ni] = Bnxt[ni];
    }
  }

  // ---- per-position block max of bf16 scores ----
  // D layout: pos row = mi*16 + g*4 + reg, proto col = ni*16 + c16.
  #pragma unroll
  for (int mi = 0; mi < 4; ++mi) {
    #pragma unroll
    for (int r = 0; r < 4; ++r) {
      float v = fmaxf(fmaxf(acc[mi][0][r], acc[mi][1][r]),
                      fmaxf(acc[mi][2][r], acc[mi][3][r]));
      #pragma unroll
      for (int s = 1; s < 16; s <<= 1) v = fmaxf(v, __shfl_xor(v, s));
      if (c16 == 0) wmax[w][(mi << 4) + (g << 2) + r] = v;
    }
  }
  __syncthreads();
  if (t < 64) {
    float bm = wmax[0][t];
    #pragma unroll
    for (int ww = 1; ww < 8; ++ww) bm = fmaxf(bm, wmax[ww][t]);
    thr[t] = bm - DELTA;
  }
  __syncthreads();

  // ---- flag candidates into LDS queue ----
  #pragma unroll
  for (int mi = 0; mi < 4; ++mi)
    #pragma unroll
    for (int ni = 0; ni < 4; ++ni)
      #pragma unroll
      for (int r = 0; r < 4; ++r) {
        int pos = (mi << 4) + (g << 2) + r;
        if (acc[mi][ni][r] >= thr[pos]) {
          int slot = atomicAdd(&qn, 1);
          if (slot < QCAP)
            queue[slot] = ((((w << 6) + (ni << 4) + c16)) << 6) | pos;
        }
      }
  __syncthreads();

  // ---- exact fp32 rescore (identical arithmetic to passing round-0) ----
  int n = qn < QCAP ? qn : QCAP;
  for (int j = t; j < n; j += 512) {
    int e = queue[j];
    int pos = e & 63, p = e >> 6;
    float a = 0.f;
    const float* pr = pnN + (p << 8);
    for (int k = 0; k < 256; ++k)
      a = fmaf(xg[(k << 10) + pos], pr[k], a);
    qscore[j] = a;
  }
  __syncthreads();

  // ---- final argmax per position (lowest index tie-break) ----
  if (t < 64) {
    float best = -3.4e38f;
    int bp = 1 << 30;
    for (int j = 0; j < n; ++j) {
      if ((queue[j] & 63) == t) {
        float s = qscore[j];
        int p = queue[j] >> 6;
        if (s > best || (s == best && p < bp)) { best = s; bp = p; }
      }
    }
    idxl[t] = bp;
    out[(size_t)NOUT + n0 + t] = (float)bp;
  }
  __syncthreads();

  // ---- recon gather: out[b][c][hw0+pos] = proto[idx[pos]][c] ----
  float* rb = out + ((size_t)b << 18) + hw0;
  #pragma unroll 1
  for (int it = 0; it < 32; ++it) {
    int lin = (it << 9) + t;
    int c = lin >> 6, pos = lin & 63;
    rb[((size_t)c << 10) + pos] = proto[(idxl[pos] << 8) + c];
  }
}

extern "C" void kernel_launch(void* const* d_in, const int* in_sizes, int n_in,
                              void* d_out, int out_size, void* d_ws, size_t ws_size,
                              hipStream_t stream) {
  const float* x = (const float*)d_in[0];        // (64, 256, 32, 32) f32
  const float* proto = (const float*)d_in[1];    // (512, 256) f32
  float* out = (float*)d_out;                    // 16777216 recon + 65536 idx
  float* pnN = (float*)d_ws;                     // 512*256 f32 = 512 KB
  ushort* pnBF = (ushort*)((char*)d_ws + 512 * 256 * sizeof(float)); // 256 KB

  proto_prep<<<512, 256, 0, stream>>>(proto, pnN, pnBF);
  match_kernel<<<NPOS / 64, 512, 0, stream>>>(x, proto, pnN, pnBF, out);
}